// Round 8
// baseline (183.043 us; speedup 1.0000x reference)
//
#include <hip/hip_runtime.h>

#define N_NODES 50000
#define N_EDGES 800000
#define D 64
#define NSLICE 4
#define SLICE_N ((N_NODES + NSLICE - 1) / NSLICE)   // 12500
#define BCAP 64        // bucket capacity; deg ~ Poisson(16), P(deg>=64) ~ 1e-19
#define XF_BLOCKS 1536 // k_xform: 6144 waves = 6/SIMD, 3072/mat
#define PRE_XF_BLOCKS 768      // transform role: 3072 waves (1536/mat)
#define PRE_FILL_BLOCKS 1280   // fill role: 320 blocks/slice

// float -> bf16 (round-to-nearest-even), as raw ushort
__device__ __forceinline__ unsigned short f2bf(float f) {
    unsigned int u = __builtin_bit_cast(unsigned int, f);
    u += 0x7fffu + ((u >> 16) & 1u);
    return (unsigned short)(u >> 16);
}
__device__ __forceinline__ float bflo(unsigned int u) {
    return __builtin_bit_cast(float, u << 16);
}
__device__ __forceinline__ float bfhi(unsigned int u) {
    return __builtin_bit_cast(float, u & 0xffff0000u);
}

// ---------------- R18 shared transform body (SGPR-operand FMA) ----------------
// Replaces the original per-4-row float4 body in k_pre's transform role.
// Old: 64 wave-uniform float4 loads per 4-row group, x2 mat-paired waves
// re-reading the same rows = 1.6M scalar-path loads streaming 12.8 MB through
// the in-order SMEM queue — the suspected k_pre pole. New: W column per lane
// in 64 VGPRs (loaded once per wave); h row wave-uniform -> 4 s_load_dwordx16
// per row feeding v_fmac v,s,v (4x fewer SMEM ops, 16 FMAs between waits).
// Ascending k, bj-seeded, one fma per k -> BIT-IDENTICAL to all prior bodies.
__device__ __forceinline__ void xform_body2(const float* __restrict__ h,
        const float* __restrict__ Ws, const float* __restrict__ Wn,
        const float* __restrict__ b,
        float* __restrict__ yS, unsigned short* __restrict__ yN,
        int gwave, int nwaves, int lane) {
    int mat = gwave & 1;
    const float* W = mat ? Wn : Ws;

    float w[D];
#pragma unroll
    for (int k = 0; k < D; ++k) w[k] = W[k * D + lane];
    float bj = mat ? 0.f : b[lane];

    int nwm = nwaves >> 1;                     // waves per mat
    for (int row = gwave >> 1; row < N_NODES; row += nwm) {
        const float* hr = h + (size_t)row * D; // wave-uniform base
        float acc = bj;
#pragma unroll
        for (int k = 0; k < D; ++k) acc = fmaf(hr[k], w[k], acc);
        if (mat) yN[(size_t)row * D + lane] = f2bf(acc);
        else     yS[(size_t)row * D + lane] = acc;
    }
}

// ---------------- FUSED stage 1: layer-0 transform ∥ CSR fill ----------
// R18 (ONLY change this round): transform role uses xform_body2.
// Fill role FROZEN (R16: slice s on XCD pair via fid&3, int4 edge loads).
// Kernel VGPR rises 40 -> ~84 (w[64]); fill occupancy ~8 -> ~6 waves/SIMD —
// fill was insensitive to blocks/resources in R11/R16, so low risk.
__global__ __launch_bounds__(256) void k_pre(const float* __restrict__ x,
        const float* __restrict__ Ws0, const float* __restrict__ Wn0,
        const float* __restrict__ b0,
        float* __restrict__ yS, unsigned short* __restrict__ yN,
        const int* __restrict__ src, const int* __restrict__ dst,
        int* __restrict__ cnt, int* __restrict__ csr) {
    int bid = (int)blockIdx.x;
    if (bid < PRE_XF_BLOCKS) {
        int lane = threadIdx.x & 63;
        int gwave = __builtin_amdgcn_readfirstlane(bid * 4 + (int)(threadIdx.x >> 6));
        xform_body2(x, Ws0, Wn0, b0, yS, yN, gwave, PRE_XF_BLOCKS * 4, lane);
    } else {
        int fid = bid - PRE_XF_BLOCKS;        // 0..1279
        int slice = fid & 3;                  // slice s on XCD pair {s, s+4}
        int lo = slice * SLICE_N, hi = lo + SLICE_N;
        int gblk = fid >> 2;                  // 0..319 within the slice
        const int4* d4p = (const int4*)dst;
        const int4* s4p = (const int4*)src;
        const int NV = N_EDGES / 4;           // 200000, exact
        const int STRIDE = (PRE_FILL_BLOCKS / 4) * 256;   // 81920
        for (int v = gblk * 256 + (int)threadIdx.x; v < NV; v += STRIDE) {
            int4 d4 = d4p[v];
            int4 s4 = s4p[v];
            if (d4.x >= lo && d4.x < hi) { int p = atomicAdd(&cnt[d4.x], 1); csr[(d4.x << 6) + p] = s4.x; }
            if (d4.y >= lo && d4.y < hi) { int p = atomicAdd(&cnt[d4.y], 1); csr[(d4.y << 6) + p] = s4.y; }
            if (d4.z >= lo && d4.z < hi) { int p = atomicAdd(&cnt[d4.z], 1); csr[(d4.z << 6) + p] = s4.z; }
            if (d4.w >= lo && d4.w < hi) { int p = atomicAdd(&cnt[d4.w], 1); csr[(d4.w << 6) + p] = s4.w; }
        }
    }
}

// ---------------- layer-1 transform (same body, R17 geometry, FROZEN) ----------
__global__ __launch_bounds__(256) void k_xform(const float* __restrict__ h,
        const float* __restrict__ Ws, const float* __restrict__ Wn,
        const float* __restrict__ b,
        float* __restrict__ yS, unsigned short* __restrict__ yN) {
    int lane = threadIdx.x & 63;
    int wid = __builtin_amdgcn_readfirstlane((int)((blockIdx.x * blockDim.x + threadIdx.x) >> 6));
    xform_body2(h, Ws, Wn, b, yS, yN, wid, (XF_BLOCKS * 256) >> 6, lane);
}

// ---------------- fused mean-aggregate + self + epilogue (R15 body, FROZEN) ----------
__global__ __launch_bounds__(256) void k_aggf(const char* __restrict__ yN,
        const float* __restrict__ yS,
        const int* __restrict__ cnt, const int* __restrict__ csr,
        float* __restrict__ out, int relu) {
    int node = __builtin_amdgcn_readfirstlane((blockIdx.x * blockDim.x + threadIdx.x) >> 6);
    int lane = threadIdx.x & 63;
    int q = lane >> 3;          // edge sub-slot 0..7
    int fq = lane & 7;          // uint4 slot within the 128 B row
    int deg = cnt[node];
    const int* bucket = csr + (node << 6);
    unsigned foff = (unsigned)fq * 16u;

    float s0 = 0.f, s1 = 0.f, s2 = 0.f, s3 = 0.f;
    float s4 = 0.f, s5 = 0.f, s6 = 0.f, s7 = 0.f;

#define ROUND16(E0)                                                         \
    {                                                                       \
        int i0 = (E0) + q, i1 = i0 + 8;                                     \
        int b0 = bucket[i0], b1 = bucket[i1];                               \
        unsigned a0 = (i0 < deg) ? ((unsigned)b0 << 7) : 0u;                \
        unsigned a1 = (i1 < deg) ? ((unsigned)b1 << 7) : 0u;                \
        float m0 = (i0 < deg) ? 1.f : 0.f;                                  \
        float m1 = (i1 < deg) ? 1.f : 0.f;                                  \
        uint4 u0 = *(const uint4*)(yN + a0 + foff);                         \
        uint4 u1 = *(const uint4*)(yN + a1 + foff);                         \
        s0 = fmaf(m0, bflo(u0.x), s0); s0 = fmaf(m1, bflo(u1.x), s0);       \
        s1 = fmaf(m0, bfhi(u0.x), s1); s1 = fmaf(m1, bfhi(u1.x), s1);       \
        s2 = fmaf(m0, bflo(u0.y), s2); s2 = fmaf(m1, bflo(u1.y), s2);       \
        s3 = fmaf(m0, bfhi(u0.y), s3); s3 = fmaf(m1, bfhi(u1.y), s3);       \
        s4 = fmaf(m0, bflo(u0.z), s4); s4 = fmaf(m1, bflo(u1.z), s4);       \
        s5 = fmaf(m0, bfhi(u0.z), s5); s5 = fmaf(m1, bfhi(u1.z), s5);       \
        s6 = fmaf(m0, bflo(u0.w), s6); s6 = fmaf(m1, bflo(u1.w), s6);       \
        s7 = fmaf(m0, bfhi(u0.w), s7); s7 = fmaf(m1, bfhi(u1.w), s7);       \
    }

    ROUND16(0)                          // unconditional: covers deg<=32 (97%)
    ROUND16(16)                         // unconditional: 8 gathers in flight
    if (deg > 32) {                     // ~3%
        ROUND16(32)
        if (deg > 48) ROUND16(48)       // ~1e-4
    }
#undef ROUND16

    s0 += __shfl_xor(s0, 8, 64); s0 += __shfl_xor(s0, 16, 64); s0 += __shfl_xor(s0, 32, 64);
    s1 += __shfl_xor(s1, 8, 64); s1 += __shfl_xor(s1, 16, 64); s1 += __shfl_xor(s1, 32, 64);
    s2 += __shfl_xor(s2, 8, 64); s2 += __shfl_xor(s2, 16, 64); s2 += __shfl_xor(s2, 32, 64);
    s3 += __shfl_xor(s3, 8, 64); s3 += __shfl_xor(s3, 16, 64); s3 += __shfl_xor(s3, 32, 64);
    s4 += __shfl_xor(s4, 8, 64); s4 += __shfl_xor(s4, 16, 64); s4 += __shfl_xor(s4, 32, 64);
    s5 += __shfl_xor(s5, 8, 64); s5 += __shfl_xor(s5, 16, 64); s5 += __shfl_xor(s5, 32, 64);
    s6 += __shfl_xor(s6, 8, 64); s6 += __shfl_xor(s6, 16, 64); s6 += __shfl_xor(s6, 32, 64);
    s7 += __shfl_xor(s7, 8, 64); s7 += __shfl_xor(s7, 16, 64); s7 += __shfl_xor(s7, 32, 64);

    float sv = (q == 0) ? s0 : (q == 1) ? s1 : (q == 2) ? s2 : (q == 3) ? s3
             : (q == 4) ? s4 : (q == 5) ? s5 : (q == 6) ? s6 : s7;
    int f = fq * 8 + q;                      // feature this lane writes
    float self = yS[(size_t)node * D + f];
    float inv = 1.0f / fmaxf((float)deg, 1.0f);
    float acc = self + sv * inv;
    if (relu) acc = fmaxf(acc, 0.f);
    out[(size_t)node * D + f] = acc;
}

extern "C" void kernel_launch(void* const* d_in, const int* in_sizes, int n_in,
                              void* d_out, int out_size, void* d_ws, size_t ws_size,
                              hipStream_t stream) {
    const float* x   = (const float*)d_in[0];
    const int*   src = (const int*)d_in[1];
    const int*   dst = (const int*)d_in[2];
    const float* Ws0 = (const float*)d_in[3];
    const float* Wn0 = (const float*)d_in[4];
    const float* b0  = (const float*)d_in[5];
    const float* Ws1 = (const float*)d_in[6];
    const float* Wn1 = (const float*)d_in[7];
    const float* b1  = (const float*)d_in[8];
    float* out = (float*)d_out;

    // workspace layout
    char* p = (char*)d_ws;
    float*          yS  = (float*)p;          p += (size_t)N_NODES * D * sizeof(float);
    unsigned short* yN  = (unsigned short*)p; p += (size_t)N_NODES * D * sizeof(unsigned short);
    int* cnt = (int*)p;                       p += (size_t)N_NODES * sizeof(int);
    int* csr = (int*)p;                       p += (size_t)N_NODES * BCAP * sizeof(int);

    const int aggBlocks = (N_NODES + 3) / 4;     // 12500: wave per node, exact

    // tiny cnt zero (200 KB), stream-ordered before the fused stage
    hipMemsetAsync(cnt, 0, (size_t)N_NODES * sizeof(int), stream);

    // stage 1: layer-0 transform ∥ CSR fill (independent, co-scheduled)
    k_pre<<<PRE_XF_BLOCKS + PRE_FILL_BLOCKS, 256, 0, stream>>>(
        x, Ws0, Wn0, b0, yS, yN, src, dst, cnt, csr);

    // layer 0 aggregate -> h in d_out
    k_aggf<<<aggBlocks, 256, 0, stream>>>((const char*)yN, yS, cnt, csr, out, 1);

    // layer 1 transform + aggregate -> d_out
    k_xform<<<XF_BLOCKS, 256, 0, stream>>>(out, Ws1, Wn1, b1, yS, yN);
    k_aggf<<<aggBlocks, 256, 0, stream>>>((const char*)yN, yS, cnt, csr, out, 0);
}